// Round 5
// baseline (3338.515 us; speedup 1.0000x reference)
//
#include <hip/hip_runtime.h>
#include <hip/hip_bf16.h>
#include <stdint.h>

#define T_TOK  8192
#define DIM_   1024
#define HID_   2816
#define NEXP   8

typedef __bf16 bf16x8 __attribute__((ext_vector_type(8)));
typedef float  f32x4  __attribute__((ext_vector_type(4)));

__device__ __forceinline__ unsigned short f2bf(float f) {
  uint32_t u = __float_as_uint(f);
  u += 0x7FFFu + ((u >> 16) & 1u);
  return (unsigned short)(u >> 16);
}
__device__ __forceinline__ float bf2f(unsigned short b) {
  return __uint_as_float(((uint32_t)b) << 16);
}

__device__ __forceinline__ void gld_lds16(const void* g, void* l) {
  __builtin_amdgcn_global_load_lds(
      (const __attribute__((address_space(1))) uint32_t*)g,
      (__attribute__((address_space(3))) uint32_t*)l, 16, 0, 0);
}

// Swizzled LDS index for a [*][64]-ushort tile: 16B unit u of row is XORed
// with (row&7). col must be a multiple of 8 (one b128 fragment).
__device__ __forceinline__ int lds_idx(int row, int col) {
  return row * 64 + ((((col >> 3) ^ (row & 7)) & 7) << 3);
}

// ---------------- cast x fp32 -> bf16 hi + lo ----------------
__global__ __launch_bounds__(256) void cast_x_kernel(const float* __restrict__ in,
                                                     unsigned short* __restrict__ hi,
                                                     unsigned short* __restrict__ lo) {
  int i = (blockIdx.x * 256 + threadIdx.x) * 8;
#pragma unroll
  for (int half = 0; half < 2; ++half) {
    float4 a = *reinterpret_cast<const float4*>(in + i + half * 4);
    ushort4 h4, l4;
    h4.x = f2bf(a.x); l4.x = f2bf(a.x - bf2f(h4.x));
    h4.y = f2bf(a.y); l4.y = f2bf(a.y - bf2f(h4.y));
    h4.z = f2bf(a.z); l4.z = f2bf(a.z - bf2f(h4.z));
    h4.w = f2bf(a.w); l4.w = f2bf(a.w - bf2f(h4.w));
    *reinterpret_cast<ushort4*>(hi + i + half * 4) = h4;
    *reinterpret_cast<ushort4*>(lo + i + half * 4) = l4;
  }
}

// ---------------- router: sigmoid top-2 + token lists ----------------
__global__ __launch_bounds__(256) void router_kernel(
    const float* __restrict__ x, const float* __restrict__ rw,
    const float* __restrict__ bias, int* __restrict__ cnt,
    int* __restrict__ list, int* __restrict__ slot, float* __restrict__ tw) {
  __shared__ float rws[NEXP * DIM_];
  for (int i = threadIdx.x; i < NEXP * DIM_ / 4; i += 256)
    reinterpret_cast<float4*>(rws)[i] = reinterpret_cast<const float4*>(rw)[i];
  __syncthreads();
  int wave = threadIdx.x >> 6, lane = threadIdx.x & 63;
  int t = blockIdx.x * 4 + wave;
  const float* xr = x + (size_t)t * DIM_;
  float p[NEXP];
#pragma unroll
  for (int e = 0; e < NEXP; ++e) p[e] = 0.f;
  for (int i = 0; i < DIM_ / 64; ++i) {
    float xv = xr[i * 64 + lane];
#pragma unroll
    for (int e = 0; e < NEXP; ++e) p[e] += xv * rws[e * DIM_ + i * 64 + lane];
  }
#pragma unroll
  for (int e = 0; e < NEXP; ++e) {
#pragma unroll
    for (int s = 32; s > 0; s >>= 1) p[e] += __shfl_xor(p[e], s);
  }
  if (lane == 0) {
    float sc[NEXP];
#pragma unroll
    for (int e = 0; e < NEXP; ++e) sc[e] = 1.f / (1.f + __expf(-(p[e] + bias[e])));
    int e0 = 0; float s0 = sc[0];
#pragma unroll
    for (int e = 1; e < NEXP; ++e) if (sc[e] > s0) { s0 = sc[e]; e0 = e; }
    int e1 = -1; float s1 = -1.f;
#pragma unroll
    for (int e = 0; e < NEXP; ++e) if (e != e0 && sc[e] > s1) { s1 = sc[e]; e1 = e; }
    float inv = 1.f / (s0 + s1 + 1e-6f);
    int p0 = atomicAdd(&cnt[e0], 1);
    list[e0 * T_TOK + p0] = t; slot[t * 2 + 0] = (e0 << 16) | p0; tw[t * 2 + 0] = s0 * inv;
    int p1 = atomicAdd(&cnt[e1], 1);
    list[e1 * T_TOK + p1] = t; slot[t * 2 + 1] = (e1 << 16) | p1; tw[t * 2 + 1] = s1 * inv;
  }
}

// ---------------- tiny exclusive scan over 8 counts ----------------
__global__ void scan_kernel(const int* __restrict__ cnt, int* __restrict__ off) {
  if (threadIdx.x == 0) {
    int a = 0;
#pragma unroll
    for (int e = 0; e < NEXP; ++e) { off[e] = a; a += cnt[e]; }
  }
}

// ---------------- fused gate+up GEMM + silu -> h (bf16) ----------------
// A = gathered x rows (hi+lo bf16 compensation); B = fp32 weights cast on the fly
// Grid: x = mb (token tile, fast-varying -> weight-slice reuse in L2/L3), y = bn.
template <bool EXPERT>
__global__ __launch_bounds__(512) void gateup_kernel(
    const unsigned short* __restrict__ xhi, const unsigned short* __restrict__ xlo,
    const float* __restrict__ gw, const float* __restrict__ uw,
    const int* __restrict__ cnt, const int* __restrict__ off,
    const int* __restrict__ list, unsigned short* __restrict__ hout) {
  const int e = EXPERT ? blockIdx.z : 0;
  const int cnt_e = EXPERT ? cnt[e] : T_TOK;
  const int mb = blockIdx.x, bn = blockIdx.y;
  if (mb * 128 >= cnt_e) return;
  const int rowoff = EXPERT ? off[e] : 0;

  __shared__ unsigned short Ah[128 * 64];
  __shared__ unsigned short Al[128 * 64];
  __shared__ unsigned short Bg[128 * 64];
  __shared__ unsigned short Bu[128 * 64];

  const int tid = threadIdx.x;
  const float* gwe = gw + (EXPERT ? (size_t)e * HID_ * DIM_ : 0);
  const float* uwe = uw + (EXPERT ? (size_t)e * HID_ * DIM_ : 0);

  // A tile: chunk c sits at LDS row r=c>>3, swizzled unit c&7; its data comes
  // from global k-unit u = (c&7)^(r&7)  (pre-swizzled source, linear LDS dest).
  size_t arow[2];
#pragma unroll
  for (int j = 0; j < 2; ++j) {
    int c = tid + j * 512;
    int r = c >> 3;
    int u = (c & 7) ^ (r & 7);
    int rl = mb * 128 + r;
    int gr;
    if (EXPERT) { int cl = rl < cnt_e ? rl : cnt_e - 1; gr = list[e * T_TOK + cl]; }
    else gr = rl;
    arow[j] = (size_t)gr * DIM_ + (size_t)(u * 8);
  }
  // B tile: float4 f -> row f>>4, 8B slot s=f&15; LDS write goes to the
  // swizzled slot ((s>>1)^(row&7))*2 + (s&1).
  size_t brow[4];
  int bwr[4];
#pragma unroll
  for (int j = 0; j < 4; ++j) {
    int f = tid + j * 512;
    int rb = f >> 4, s = f & 15;
    bwr[j] = rb * 64 + (((s >> 1) ^ (rb & 7)) * 2 + (s & 1)) * 4;
    brow[j] = (size_t)(bn * 128 + rb) * DIM_ + (size_t)(s * 4);
  }

  const f32x4 vzero = {0.f, 0.f, 0.f, 0.f};
  f32x4 accg[4][2], accu[4][2];
#pragma unroll
  for (int m = 0; m < 4; ++m)
#pragma unroll
    for (int n = 0; n < 2; ++n) { accg[m][n] = vzero; accu[m][n] = vzero; }

  const int wid = tid >> 6, lane = tid & 63;
  const int wm = wid >> 2, wn = wid & 3;
  const int fr = lane & 15, fk = (lane >> 4) * 8;

  for (int k0 = 0; k0 < DIM_; k0 += 64) {
    __syncthreads();
#pragma unroll
    for (int j = 0; j < 2; ++j) {
      int c = tid + j * 512;
      gld_lds16(xhi + arow[j] + k0, &Ah[c * 8]);
      gld_lds16(xlo + arow[j] + k0, &Al[c * 8]);
    }
#pragma unroll
    for (int j = 0; j < 4; ++j) {
      float4 vg = *reinterpret_cast<const float4*>(gwe + brow[j] + k0);
      float4 vu = *reinterpret_cast<const float4*>(uwe + brow[j] + k0);
      ushort4 wg; wg.x = f2bf(vg.x); wg.y = f2bf(vg.y); wg.z = f2bf(vg.z); wg.w = f2bf(vg.w);
      ushort4 wu; wu.x = f2bf(vu.x); wu.y = f2bf(vu.y); wu.z = f2bf(vu.z); wu.w = f2bf(vu.w);
      *reinterpret_cast<ushort4*>(&Bg[bwr[j]]) = wg;
      *reinterpret_cast<ushort4*>(&Bu[bwr[j]]) = wu;
    }
    __syncthreads();
#pragma unroll
    for (int kk = 0; kk < 64; kk += 32) {
      bf16x8 ah[4], al[4], bg[2], bu[2];
#pragma unroll
      for (int m = 0; m < 4; ++m) {
        int ar = wm * 64 + m * 16 + fr;
        ah[m] = *reinterpret_cast<const bf16x8*>(&Ah[lds_idx(ar, kk + fk)]);
        al[m] = *reinterpret_cast<const bf16x8*>(&Al[lds_idx(ar, kk + fk)]);
      }
#pragma unroll
      for (int n = 0; n < 2; ++n) {
        int br = wn * 32 + n * 16 + fr;
        bg[n] = *reinterpret_cast<const bf16x8*>(&Bg[lds_idx(br, kk + fk)]);
        bu[n] = *reinterpret_cast<const bf16x8*>(&Bu[lds_idx(br, kk + fk)]);
      }
#pragma unroll
      for (int m = 0; m < 4; ++m)
#pragma unroll
        for (int n = 0; n < 2; ++n) {
          accg[m][n] = __builtin_amdgcn_mfma_f32_16x16x32_bf16(ah[m], bg[n], accg[m][n], 0, 0, 0);
          accg[m][n] = __builtin_amdgcn_mfma_f32_16x16x32_bf16(al[m], bg[n], accg[m][n], 0, 0, 0);
          accu[m][n] = __builtin_amdgcn_mfma_f32_16x16x32_bf16(ah[m], bu[n], accu[m][n], 0, 0, 0);
          accu[m][n] = __builtin_amdgcn_mfma_f32_16x16x32_bf16(al[m], bu[n], accu[m][n], 0, 0, 0);
        }
    }
  }

  const int rb = mb * 128 + wm * 64 + (lane >> 4) * 4;
  const int cb = bn * 128 + wn * 32 + fr;
#pragma unroll
  for (int m = 0; m < 4; ++m) {
#pragma unroll
    for (int r = 0; r < 4; ++r) {
      int rl = rb + m * 16 + r;
      if (EXPERT && rl >= cnt_e) continue;
      size_t rowbase = (size_t)(rowoff + rl) * HID_ + cb;
#pragma unroll
      for (int n = 0; n < 2; ++n) {
        float g = accg[m][n][r], u = accu[m][n][r];
        float hv = (g / (1.f + __expf(-g))) * u;
        hout[rowbase + n * 16] = f2bf(hv);
      }
    }
  }
}

// ---------------- down GEMM: y = h . dw^T (fp32 out, unweighted) ----------------
template <bool EXPERT>
__global__ __launch_bounds__(512) void down_kernel(
    const unsigned short* __restrict__ h, const float* __restrict__ dw,
    const int* __restrict__ cnt, const int* __restrict__ off,
    float* __restrict__ yout) {
  const int e = EXPERT ? blockIdx.z : 0;
  const int cnt_e = EXPERT ? cnt[e] : T_TOK;
  const int mb = blockIdx.x, bn = blockIdx.y;
  if (mb * 128 >= cnt_e) return;
  const int rowoff = EXPERT ? off[e] : 0;

  __shared__ unsigned short As[128 * 64];
  __shared__ unsigned short Bs[128 * 64];

  const int tid = threadIdx.x;
  const float* dwe = dw + (EXPERT ? (size_t)e * DIM_ * HID_ : 0);

  size_t arow[2];
#pragma unroll
  for (int j = 0; j < 2; ++j) {
    int c = tid + j * 512;
    int r = c >> 3;
    int u = (c & 7) ^ (r & 7);
    int rl = mb * 128 + r;
    arow[j] = (size_t)(rowoff + rl) * HID_ + (size_t)(u * 8);
  }
  size_t brow[4];
  int bwr[4];
#pragma unroll
  for (int j = 0; j < 4; ++j) {
    int f = tid + j * 512;
    int rb = f >> 4, s = f & 15;
    bwr[j] = rb * 64 + (((s >> 1) ^ (rb & 7)) * 2 + (s & 1)) * 4;
    brow[j] = (size_t)(bn * 128 + rb) * HID_ + (size_t)(s * 4);
  }

  const f32x4 vzero = {0.f, 0.f, 0.f, 0.f};
  f32x4 acc[4][2];
#pragma unroll
  for (int m = 0; m < 4; ++m)
#pragma unroll
    for (int n = 0; n < 2; ++n) acc[m][n] = vzero;

  const int wid = tid >> 6, lane = tid & 63;
  const int wm = wid >> 2, wn = wid & 3;
  const int fr = lane & 15, fk = (lane >> 4) * 8;

  for (int k0 = 0; k0 < HID_; k0 += 64) {
    __syncthreads();
#pragma unroll
    for (int j = 0; j < 2; ++j) {
      int c = tid + j * 512;
      gld_lds16(h + arow[j] + k0, &As[c * 8]);
    }
#pragma unroll
    for (int j = 0; j < 4; ++j) {
      float4 v = *reinterpret_cast<const float4*>(dwe + brow[j] + k0);
      ushort4 w; w.x = f2bf(v.x); w.y = f2bf(v.y); w.z = f2bf(v.z); w.w = f2bf(v.w);
      *reinterpret_cast<ushort4*>(&Bs[bwr[j]]) = w;
    }
    __syncthreads();
#pragma unroll
    for (int kk = 0; kk < 64; kk += 32) {
      bf16x8 a[4], b[2];
#pragma unroll
      for (int m = 0; m < 4; ++m) {
        int ar = wm * 64 + m * 16 + fr;
        a[m] = *reinterpret_cast<const bf16x8*>(&As[lds_idx(ar, kk + fk)]);
      }
#pragma unroll
      for (int n = 0; n < 2; ++n) {
        int br = wn * 32 + n * 16 + fr;
        b[n] = *reinterpret_cast<const bf16x8*>(&Bs[lds_idx(br, kk + fk)]);
      }
#pragma unroll
      for (int m = 0; m < 4; ++m)
#pragma unroll
        for (int n = 0; n < 2; ++n)
          acc[m][n] = __builtin_amdgcn_mfma_f32_16x16x32_bf16(a[m], b[n], acc[m][n], 0, 0, 0);
    }
  }

  const int rb = mb * 128 + wm * 64 + (lane >> 4) * 4;
  const int cb = bn * 128 + wn * 32 + fr;
#pragma unroll
  for (int m = 0; m < 4; ++m) {
#pragma unroll
    for (int r = 0; r < 4; ++r) {
      int rl = rb + m * 16 + r;
      if (EXPERT && rl >= cnt_e) continue;
#pragma unroll
      for (int n = 0; n < 2; ++n)
        yout[(size_t)(rowoff + rl) * DIM_ + cb + n * 16] = acc[m][n][r];
    }
  }
}

// ---------------- finalize: out = y_shared + w0*y0 + w1*y1 ----------------
__global__ __launch_bounds__(256) void finalize_kernel(
    const float* __restrict__ ys, const float* __restrict__ yb,
    const int* __restrict__ slot, const float* __restrict__ tw,
    const int* __restrict__ off, float* __restrict__ out) {
  int i = blockIdx.x * 256 + threadIdx.x;
  int t = i >> 8, c4 = (i & 255) * 4;
  int s0 = slot[t * 2], s1 = slot[t * 2 + 1];
  float w0 = tw[t * 2], w1 = tw[t * 2 + 1];
  size_t r0 = (size_t)(off[s0 >> 16] + (s0 & 0xFFFF)) * DIM_ + c4;
  size_t r1 = (size_t)(off[s1 >> 16] + (s1 & 0xFFFF)) * DIM_ + c4;
  float4 a  = *reinterpret_cast<const float4*>(ys + (size_t)t * DIM_ + c4);
  float4 b0 = *reinterpret_cast<const float4*>(yb + r0);
  float4 b1 = *reinterpret_cast<const float4*>(yb + r1);
  float4 o;
  o.x = a.x + w0 * b0.x + w1 * b1.x;
  o.y = a.y + w0 * b0.y + w1 * b1.y;
  o.z = a.z + w0 * b0.z + w1 * b1.z;
  o.w = a.w + w0 * b0.w + w1 * b1.w;
  *reinterpret_cast<float4*>(out + (size_t)t * DIM_ + c4) = o;
}

extern "C" void kernel_launch(void* const* d_in, const int* in_sizes, int n_in,
                              void* d_out, int out_size, void* d_ws, size_t ws_size,
                              hipStream_t stream) {
  const float* x    = (const float*)d_in[0];
  const float* rw   = (const float*)d_in[1];
  const float* bias = (const float*)d_in[2];
  const float* gw   = (const float*)d_in[3];
  const float* uw   = (const float*)d_in[4];
  const float* dwn  = (const float*)d_in[5];
  const float* sgw  = (const float*)d_in[6];
  const float* suw  = (const float*)d_in[7];
  const float* sdw  = (const float*)d_in[8];
  float* out = (float*)d_out;

  char* ws = (char*)d_ws;
  size_t o = 0;
  auto alloc = [&](size_t b) { size_t r = o; o = (o + b + 255) & ~(size_t)255; return r; };
  unsigned short* xhi = (unsigned short*)(ws + alloc((size_t)T_TOK * DIM_ * 2));
  unsigned short* xlo = (unsigned short*)(ws + alloc((size_t)T_TOK * DIM_ * 2));
  unsigned short* h   = (unsigned short*)(ws + alloc(((size_t)2 * T_TOK + 128) * HID_ * 2));
  float* yshared = (float*)(ws + alloc((size_t)T_TOK * DIM_ * 4));
  float* ybuf    = (float*)(ws + alloc((size_t)2 * T_TOK * DIM_ * 4));
  int* cnt  = (int*)(ws + alloc(NEXP * 4));
  int* off  = (int*)(ws + alloc(NEXP * 4));
  int* list = (int*)(ws + alloc((size_t)NEXP * T_TOK * 4));
  int* slot = (int*)(ws + alloc((size_t)2 * T_TOK * 4));
  float* tw = (float*)(ws + alloc((size_t)2 * T_TOK * 4));
  if (o > ws_size) {  // not enough scratch: fail visibly, don't corrupt
    hipMemsetAsync(d_out, 0, (size_t)out_size * 4, stream);
    return;
  }

  hipMemsetAsync(cnt, 0, NEXP * 4, stream);
  cast_x_kernel<<<T_TOK * DIM_ / 8 / 256, 256, 0, stream>>>(x, xhi, xlo);
  router_kernel<<<T_TOK / 4, 256, 0, stream>>>(x, rw, bias, cnt, list, slot, tw);
  scan_kernel<<<1, 64, 0, stream>>>(cnt, off);
  // shared expert
  gateup_kernel<false><<<dim3(T_TOK / 128, HID_ / 128, 1), 512, 0, stream>>>(
      xhi, xlo, sgw, suw, cnt, off, list, h);
  down_kernel<false><<<dim3(T_TOK / 128, DIM_ / 128, 1), 512, 0, stream>>>(
      h, sdw, cnt, off, yshared);
  // routed experts (worst-case grid, early-exit on cnt)
  gateup_kernel<true><<<dim3(T_TOK / 128, HID_ / 128, NEXP), 512, 0, stream>>>(
      xhi, xlo, gw, uw, cnt, off, list, h);
  down_kernel<true><<<dim3(T_TOK / 128, DIM_ / 128, NEXP), 512, 0, stream>>>(
      h, dwn, cnt, off, ybuf);
  finalize_kernel<<<T_TOK * (DIM_ / 4) / 256, 256, 0, stream>>>(
      yshared, ybuf, slot, tw, off, out);
}

// Round 6
// 2168.788 us; speedup vs baseline: 1.5393x; 1.5393x over previous
//
#include <hip/hip_runtime.h>
#include <hip/hip_bf16.h>
#include <stdint.h>

#define T_TOK  8192
#define DIM_   1024
#define HID_   2816
#define NEXP   8

typedef __bf16 bf16x8 __attribute__((ext_vector_type(8)));
typedef float  f32x4  __attribute__((ext_vector_type(4)));

__device__ __forceinline__ unsigned short f2bf(float f) {
  uint32_t u = __float_as_uint(f);
  u += 0x7FFFu + ((u >> 16) & 1u);
  return (unsigned short)(u >> 16);
}
__device__ __forceinline__ float bf2f(unsigned short b) {
  return __uint_as_float(((uint32_t)b) << 16);
}

__device__ __forceinline__ void gld_lds16(const void* g, void* l) {
  __builtin_amdgcn_global_load_lds(
      (const __attribute__((address_space(1))) uint32_t*)g,
      (__attribute__((address_space(3))) uint32_t*)l, 16, 0, 0);
}

// Swizzled LDS index for a [*][64]-ushort tile: 16B unit (col>>3) XOR (row&7).
__device__ __forceinline__ int lds_idx(int row, int col) {
  return row * 64 + ((((col >> 3) ^ (row & 7)) & 7) << 3);
}

// ---------------- cast x fp32 -> bf16 hi + lo ----------------
__global__ __launch_bounds__(256) void cast_x_kernel(const float* __restrict__ in,
                                                     unsigned short* __restrict__ hi,
                                                     unsigned short* __restrict__ lo) {
  int i = (blockIdx.x * 256 + threadIdx.x) * 8;
#pragma unroll
  for (int half = 0; half < 2; ++half) {
    float4 a = *reinterpret_cast<const float4*>(in + i + half * 4);
    ushort4 h4, l4;
    h4.x = f2bf(a.x); l4.x = f2bf(a.x - bf2f(h4.x));
    h4.y = f2bf(a.y); l4.y = f2bf(a.y - bf2f(h4.y));
    h4.z = f2bf(a.z); l4.z = f2bf(a.z - bf2f(h4.z));
    h4.w = f2bf(a.w); l4.w = f2bf(a.w - bf2f(h4.w));
    *reinterpret_cast<ushort4*>(hi + i + half * 4) = h4;
    *reinterpret_cast<ushort4*>(lo + i + half * 4) = l4;
  }
}

// ---------------- cast weights fp32 -> bf16 (exact grid, no bounds) ----------------
__global__ __launch_bounds__(256) void cast_w_kernel(const float* __restrict__ in,
                                                     unsigned short* __restrict__ out) {
  size_t i = ((size_t)blockIdx.x * 256 + threadIdx.x) * 8;
#pragma unroll
  for (int half = 0; half < 2; ++half) {
    float4 a = *reinterpret_cast<const float4*>(in + i + half * 4);
    ushort4 h4;
    h4.x = f2bf(a.x); h4.y = f2bf(a.y); h4.z = f2bf(a.z); h4.w = f2bf(a.w);
    *reinterpret_cast<ushort4*>(out + i + half * 4) = h4;
  }
}

// ---------------- router: sigmoid top-2 + token lists ----------------
__global__ __launch_bounds__(256) void router_kernel(
    const float* __restrict__ x, const float* __restrict__ rw,
    const float* __restrict__ bias, int* __restrict__ cnt,
    int* __restrict__ list, int* __restrict__ slot, float* __restrict__ tw) {
  __shared__ float rws[NEXP * DIM_];
  for (int i = threadIdx.x; i < NEXP * DIM_ / 4; i += 256)
    reinterpret_cast<float4*>(rws)[i] = reinterpret_cast<const float4*>(rw)[i];
  __syncthreads();
  int wave = threadIdx.x >> 6, lane = threadIdx.x & 63;
  int t = blockIdx.x * 4 + wave;
  const float* xr = x + (size_t)t * DIM_;
  float p[NEXP];
#pragma unroll
  for (int e = 0; e < NEXP; ++e) p[e] = 0.f;
  for (int i = 0; i < DIM_ / 64; ++i) {
    float xv = xr[i * 64 + lane];
#pragma unroll
    for (int e = 0; e < NEXP; ++e) p[e] += xv * rws[e * DIM_ + i * 64 + lane];
  }
#pragma unroll
  for (int e = 0; e < NEXP; ++e) {
#pragma unroll
    for (int s = 32; s > 0; s >>= 1) p[e] += __shfl_xor(p[e], s);
  }
  if (lane == 0) {
    float sc[NEXP];
#pragma unroll
    for (int e = 0; e < NEXP; ++e) sc[e] = 1.f / (1.f + __expf(-(p[e] + bias[e])));
    int e0 = 0; float s0 = sc[0];
#pragma unroll
    for (int e = 1; e < NEXP; ++e) if (sc[e] > s0) { s0 = sc[e]; e0 = e; }
    int e1 = -1; float s1 = -1.f;
#pragma unroll
    for (int e = 0; e < NEXP; ++e) if (e != e0 && sc[e] > s1) { s1 = sc[e]; e1 = e; }
    float inv = 1.f / (s0 + s1 + 1e-6f);
    int p0 = atomicAdd(&cnt[e0], 1);
    list[e0 * T_TOK + p0] = t; slot[t * 2 + 0] = (e0 << 16) | p0; tw[t * 2 + 0] = s0 * inv;
    int p1 = atomicAdd(&cnt[e1], 1);
    list[e1 * T_TOK + p1] = t; slot[t * 2 + 1] = (e1 << 16) | p1; tw[t * 2 + 1] = s1 * inv;
  }
}

// ---------------- tiny exclusive scan over 8 counts ----------------
__global__ void scan_kernel(const int* __restrict__ cnt, int* __restrict__ off) {
  if (threadIdx.x == 0) {
    int a = 0;
#pragma unroll
    for (int e = 0; e < NEXP; ++e) { off[e] = a; a += cnt[e]; }
  }
}

// ==================================================================
// bf16-weight path: B staged via global_load_lds with pre-swizzled src
// Grid: x = bn (fast -> shared A slice, many independent B streams), y = mb.
// ==================================================================
template <bool EXPERT>
__global__ __launch_bounds__(512) void gateup_bf16(
    const unsigned short* __restrict__ xhi, const unsigned short* __restrict__ xlo,
    const unsigned short* __restrict__ gwb, const unsigned short* __restrict__ uwb,
    const int* __restrict__ cnt, const int* __restrict__ off,
    const int* __restrict__ list, unsigned short* __restrict__ hout) {
  const int e = EXPERT ? blockIdx.z : 0;
  const int cnt_e = EXPERT ? cnt[e] : T_TOK;
  const int bn = blockIdx.x, mb = blockIdx.y;
  if (mb * 128 >= cnt_e) return;
  const int rowoff = EXPERT ? off[e] : 0;

  __shared__ unsigned short Ah[128 * 64];
  __shared__ unsigned short Al[128 * 64];
  __shared__ unsigned short Bg[128 * 64];
  __shared__ unsigned short Bu[128 * 64];

  const int tid = threadIdx.x;
  const unsigned short* gwe = gwb + (EXPERT ? (size_t)e * HID_ * DIM_ : 0);
  const unsigned short* uwe = uwb + (EXPERT ? (size_t)e * HID_ * DIM_ : 0);

  // chunk c -> LDS row r=c>>3, unit c&7; global k-unit u = (c&7)^(r&7)
  size_t arow[2], brow[2];
#pragma unroll
  for (int j = 0; j < 2; ++j) {
    int c = tid + j * 512;
    int r = c >> 3;
    int u = (c & 7) ^ (r & 7);
    int rl = mb * 128 + r;
    int gr;
    if (EXPERT) { int cl = rl < cnt_e ? rl : cnt_e - 1; gr = list[e * T_TOK + cl]; }
    else gr = rl;
    arow[j] = (size_t)gr * DIM_ + (size_t)(u * 8);
    brow[j] = (size_t)(bn * 128 + r) * DIM_ + (size_t)(u * 8);
  }

  const f32x4 vzero = {0.f, 0.f, 0.f, 0.f};
  f32x4 accg[4][2], accu[4][2];
#pragma unroll
  for (int m = 0; m < 4; ++m)
#pragma unroll
    for (int n = 0; n < 2; ++n) { accg[m][n] = vzero; accu[m][n] = vzero; }

  const int wid = tid >> 6, lane = tid & 63;
  const int wm = wid >> 2, wn = wid & 3;
  const int fr = lane & 15, fk = (lane >> 4) * 8;

  for (int k0 = 0; k0 < DIM_; k0 += 64) {
    __syncthreads();
#pragma unroll
    for (int j = 0; j < 2; ++j) {
      int c = tid + j * 512;
      gld_lds16(xhi + arow[j] + k0, &Ah[c * 8]);
      gld_lds16(xlo + arow[j] + k0, &Al[c * 8]);
      gld_lds16(gwe + brow[j] + k0, &Bg[c * 8]);
      gld_lds16(uwe + brow[j] + k0, &Bu[c * 8]);
    }
    __syncthreads();
#pragma unroll
    for (int kk = 0; kk < 64; kk += 32) {
      bf16x8 ah[4], al[4], bg[2], bu[2];
#pragma unroll
      for (int m = 0; m < 4; ++m) {
        int ar = wm * 64 + m * 16 + fr;
        ah[m] = *reinterpret_cast<const bf16x8*>(&Ah[lds_idx(ar, kk + fk)]);
        al[m] = *reinterpret_cast<const bf16x8*>(&Al[lds_idx(ar, kk + fk)]);
      }
#pragma unroll
      for (int n = 0; n < 2; ++n) {
        int br = wn * 32 + n * 16 + fr;
        bg[n] = *reinterpret_cast<const bf16x8*>(&Bg[lds_idx(br, kk + fk)]);
        bu[n] = *reinterpret_cast<const bf16x8*>(&Bu[lds_idx(br, kk + fk)]);
      }
#pragma unroll
      for (int m = 0; m < 4; ++m)
#pragma unroll
        for (int n = 0; n < 2; ++n) {
          accg[m][n] = __builtin_amdgcn_mfma_f32_16x16x32_bf16(ah[m], bg[n], accg[m][n], 0, 0, 0);
          accg[m][n] = __builtin_amdgcn_mfma_f32_16x16x32_bf16(al[m], bg[n], accg[m][n], 0, 0, 0);
          accu[m][n] = __builtin_amdgcn_mfma_f32_16x16x32_bf16(ah[m], bu[n], accu[m][n], 0, 0, 0);
          accu[m][n] = __builtin_amdgcn_mfma_f32_16x16x32_bf16(al[m], bu[n], accu[m][n], 0, 0, 0);
        }
    }
  }

  const int rb = mb * 128 + wm * 64 + (lane >> 4) * 4;
  const int cb = bn * 128 + wn * 32 + fr;
#pragma unroll
  for (int m = 0; m < 4; ++m) {
#pragma unroll
    for (int r = 0; r < 4; ++r) {
      int rl = rb + m * 16 + r;
      if (EXPERT && rl >= cnt_e) continue;
      size_t rowbase = (size_t)(rowoff + rl) * HID_ + cb;
#pragma unroll
      for (int n = 0; n < 2; ++n) {
        float g = accg[m][n][r], u = accu[m][n][r];
        float hv = (g / (1.f + __expf(-g))) * u;
        hout[rowbase + n * 16] = f2bf(hv);
      }
    }
  }
}

template <bool EXPERT>
__global__ __launch_bounds__(512) void down_bf16(
    const unsigned short* __restrict__ h, const unsigned short* __restrict__ dwb,
    const int* __restrict__ cnt, const int* __restrict__ off,
    float* __restrict__ yout) {
  const int e = EXPERT ? blockIdx.z : 0;
  const int cnt_e = EXPERT ? cnt[e] : T_TOK;
  const int bn = blockIdx.x, mb = blockIdx.y;
  if (mb * 128 >= cnt_e) return;
  const int rowoff = EXPERT ? off[e] : 0;

  __shared__ unsigned short As[128 * 64];
  __shared__ unsigned short Bs[128 * 64];

  const int tid = threadIdx.x;
  const unsigned short* dwe = dwb + (EXPERT ? (size_t)e * DIM_ * HID_ : 0);

  size_t arow[2], brow[2];
#pragma unroll
  for (int j = 0; j < 2; ++j) {
    int c = tid + j * 512;
    int r = c >> 3;
    int u = (c & 7) ^ (r & 7);
    arow[j] = (size_t)(rowoff + mb * 128 + r) * HID_ + (size_t)(u * 8);
    brow[j] = (size_t)(bn * 128 + r) * HID_ + (size_t)(u * 8);
  }

  const f32x4 vzero = {0.f, 0.f, 0.f, 0.f};
  f32x4 acc[4][2];
#pragma unroll
  for (int m = 0; m < 4; ++m)
#pragma unroll
    for (int n = 0; n < 2; ++n) acc[m][n] = vzero;

  const int wid = tid >> 6, lane = tid & 63;
  const int wm = wid >> 2, wn = wid & 3;
  const int fr = lane & 15, fk = (lane >> 4) * 8;

  for (int k0 = 0; k0 < HID_; k0 += 64) {
    __syncthreads();
#pragma unroll
    for (int j = 0; j < 2; ++j) {
      int c = tid + j * 512;
      gld_lds16(h + arow[j] + k0, &As[c * 8]);
      gld_lds16(dwe + brow[j] + k0, &Bs[c * 8]);
    }
    __syncthreads();
#pragma unroll
    for (int kk = 0; kk < 64; kk += 32) {
      bf16x8 a[4], b[2];
#pragma unroll
      for (int m = 0; m < 4; ++m) {
        int ar = wm * 64 + m * 16 + fr;
        a[m] = *reinterpret_cast<const bf16x8*>(&As[lds_idx(ar, kk + fk)]);
      }
#pragma unroll
      for (int n = 0; n < 2; ++n) {
        int br = wn * 32 + n * 16 + fr;
        b[n] = *reinterpret_cast<const bf16x8*>(&Bs[lds_idx(br, kk + fk)]);
      }
#pragma unroll
      for (int m = 0; m < 4; ++m)
#pragma unroll
        for (int n = 0; n < 2; ++n)
          acc[m][n] = __builtin_amdgcn_mfma_f32_16x16x32_bf16(a[m], b[n], acc[m][n], 0, 0, 0);
    }
  }

  const int rb = mb * 128 + wm * 64 + (lane >> 4) * 4;
  const int cb = bn * 128 + wn * 32 + fr;
#pragma unroll
  for (int m = 0; m < 4; ++m) {
#pragma unroll
    for (int r = 0; r < 4; ++r) {
      int rl = rb + m * 16 + r;
      if (EXPERT && rl >= cnt_e) continue;
#pragma unroll
      for (int n = 0; n < 2; ++n)
        yout[(size_t)(rowoff + rl) * DIM_ + cb + n * 16] = acc[m][n][r];
    }
  }
}

// ==================================================================
// Fallback fp32-weight path (reg-stage + convert), v1 grid order.
// ==================================================================
template <bool EXPERT>
__global__ __launch_bounds__(512) void gateup_kernel(
    const unsigned short* __restrict__ xhi, const unsigned short* __restrict__ xlo,
    const float* __restrict__ gw, const float* __restrict__ uw,
    const int* __restrict__ cnt, const int* __restrict__ off,
    const int* __restrict__ list, unsigned short* __restrict__ hout) {
  const int e = EXPERT ? blockIdx.z : 0;
  const int cnt_e = EXPERT ? cnt[e] : T_TOK;
  const int bn = blockIdx.x, mb = blockIdx.y;
  if (mb * 128 >= cnt_e) return;
  const int rowoff = EXPERT ? off[e] : 0;

  __shared__ unsigned short Ah[128 * 64];
  __shared__ unsigned short Al[128 * 64];
  __shared__ unsigned short Bg[128 * 64];
  __shared__ unsigned short Bu[128 * 64];

  const int tid = threadIdx.x;
  const float* gwe = gw + (EXPERT ? (size_t)e * HID_ * DIM_ : 0);
  const float* uwe = uw + (EXPERT ? (size_t)e * HID_ * DIM_ : 0);

  size_t arow[2];
#pragma unroll
  for (int j = 0; j < 2; ++j) {
    int c = tid + j * 512;
    int r = c >> 3;
    int u = (c & 7) ^ (r & 7);
    int rl = mb * 128 + r;
    int gr;
    if (EXPERT) { int cl = rl < cnt_e ? rl : cnt_e - 1; gr = list[e * T_TOK + cl]; }
    else gr = rl;
    arow[j] = (size_t)gr * DIM_ + (size_t)(u * 8);
  }
  size_t brow[4];
  int bwr[4];
#pragma unroll
  for (int j = 0; j < 4; ++j) {
    int f = tid + j * 512;
    int rb = f >> 4, s = f & 15;
    bwr[j] = rb * 64 + (((s >> 1) ^ (rb & 7)) * 2 + (s & 1)) * 4;
    brow[j] = (size_t)(bn * 128 + rb) * DIM_ + (size_t)(s * 4);
  }

  const f32x4 vzero = {0.f, 0.f, 0.f, 0.f};
  f32x4 accg[4][2], accu[4][2];
#pragma unroll
  for (int m = 0; m < 4; ++m)
#pragma unroll
    for (int n = 0; n < 2; ++n) { accg[m][n] = vzero; accu[m][n] = vzero; }

  const int wid = tid >> 6, lane = tid & 63;
  const int wm = wid >> 2, wn = wid & 3;
  const int fr = lane & 15, fk = (lane >> 4) * 8;

  for (int k0 = 0; k0 < DIM_; k0 += 64) {
    __syncthreads();
#pragma unroll
    for (int j = 0; j < 2; ++j) {
      int c = tid + j * 512;
      gld_lds16(xhi + arow[j] + k0, &Ah[c * 8]);
      gld_lds16(xlo + arow[j] + k0, &Al[c * 8]);
    }
#pragma unroll
    for (int j = 0; j < 4; ++j) {
      float4 vg = *reinterpret_cast<const float4*>(gwe + brow[j] + k0);
      float4 vu = *reinterpret_cast<const float4*>(uwe + brow[j] + k0);
      ushort4 wg; wg.x = f2bf(vg.x); wg.y = f2bf(vg.y); wg.z = f2bf(vg.z); wg.w = f2bf(vg.w);
      ushort4 wu; wu.x = f2bf(vu.x); wu.y = f2bf(vu.y); wu.z = f2bf(vu.z); wu.w = f2bf(vu.w);
      *reinterpret_cast<ushort4*>(&Bg[bwr[j]]) = wg;
      *reinterpret_cast<ushort4*>(&Bu[bwr[j]]) = wu;
    }
    __syncthreads();
#pragma unroll
    for (int kk = 0; kk < 64; kk += 32) {
      bf16x8 ah[4], al[4], bg[2], bu[2];
#pragma unroll
      for (int m = 0; m < 4; ++m) {
        int ar = wm * 64 + m * 16 + fr;
        ah[m] = *reinterpret_cast<const bf16x8*>(&Ah[lds_idx(ar, kk + fk)]);
        al[m] = *reinterpret_cast<const bf16x8*>(&Al[lds_idx(ar, kk + fk)]);
      }
#pragma unroll
      for (int n = 0; n < 2; ++n) {
        int br = wn * 32 + n * 16 + fr;
        bg[n] = *reinterpret_cast<const bf16x8*>(&Bg[lds_idx(br, kk + fk)]);
        bu[n] = *reinterpret_cast<const bf16x8*>(&Bu[lds_idx(br, kk + fk)]);
      }
#pragma unroll
      for (int m = 0; m < 4; ++m)
#pragma unroll
        for (int n = 0; n < 2; ++n) {
          accg[m][n] = __builtin_amdgcn_mfma_f32_16x16x32_bf16(ah[m], bg[n], accg[m][n], 0, 0, 0);
          accg[m][n] = __builtin_amdgcn_mfma_f32_16x16x32_bf16(al[m], bg[n], accg[m][n], 0, 0, 0);
          accu[m][n] = __builtin_amdgcn_mfma_f32_16x16x32_bf16(ah[m], bu[n], accu[m][n], 0, 0, 0);
          accu[m][n] = __builtin_amdgcn_mfma_f32_16x16x32_bf16(al[m], bu[n], accu[m][n], 0, 0, 0);
        }
    }
  }

  const int rb = mb * 128 + wm * 64 + (lane >> 4) * 4;
  const int cb = bn * 128 + wn * 32 + fr;
#pragma unroll
  for (int m = 0; m < 4; ++m) {
#pragma unroll
    for (int r = 0; r < 4; ++r) {
      int rl = rb + m * 16 + r;
      if (EXPERT && rl >= cnt_e) continue;
      size_t rowbase = (size_t)(rowoff + rl) * HID_ + cb;
#pragma unroll
      for (int n = 0; n < 2; ++n) {
        float g = accg[m][n][r], u = accu[m][n][r];
        float hv = (g / (1.f + __expf(-g))) * u;
        hout[rowbase + n * 16] = f2bf(hv);
      }
    }
  }
}

template <bool EXPERT>
__global__ __launch_bounds__(512) void down_kernel(
    const unsigned short* __restrict__ h, const float* __restrict__ dw,
    const int* __restrict__ cnt, const int* __restrict__ off,
    float* __restrict__ yout) {
  const int e = EXPERT ? blockIdx.z : 0;
  const int cnt_e = EXPERT ? cnt[e] : T_TOK;
  const int bn = blockIdx.x, mb = blockIdx.y;
  if (mb * 128 >= cnt_e) return;
  const int rowoff = EXPERT ? off[e] : 0;

  __shared__ unsigned short As[128 * 64];
  __shared__ unsigned short Bs[128 * 64];

  const int tid = threadIdx.x;
  const float* dwe = dw + (EXPERT ? (size_t)e * DIM_ * HID_ : 0);

  size_t arow[2];
#pragma unroll
  for (int j = 0; j < 2; ++j) {
    int c = tid + j * 512;
    int r = c >> 3;
    int u = (c & 7) ^ (r & 7);
    arow[j] = (size_t)(rowoff + mb * 128 + r) * HID_ + (size_t)(u * 8);
  }
  size_t brow[4];
  int bwr[4];
#pragma unroll
  for (int j = 0; j < 4; ++j) {
    int f = tid + j * 512;
    int rb = f >> 4, s = f & 15;
    bwr[j] = rb * 64 + (((s >> 1) ^ (rb & 7)) * 2 + (s & 1)) * 4;
    brow[j] = (size_t)(bn * 128 + rb) * HID_ + (size_t)(s * 4);
  }

  const f32x4 vzero = {0.f, 0.f, 0.f, 0.f};
  f32x4 acc[4][2];
#pragma unroll
  for (int m = 0; m < 4; ++m)
#pragma unroll
    for (int n = 0; n < 2; ++n) acc[m][n] = vzero;

  const int wid = tid >> 6, lane = tid & 63;
  const int wm = wid >> 2, wn = wid & 3;
  const int fr = lane & 15, fk = (lane >> 4) * 8;

  for (int k0 = 0; k0 < HID_; k0 += 64) {
    __syncthreads();
#pragma unroll
    for (int j = 0; j < 2; ++j) {
      int c = tid + j * 512;
      gld_lds16(h + arow[j] + k0, &As[c * 8]);
    }
#pragma unroll
    for (int j = 0; j < 4; ++j) {
      float4 v = *reinterpret_cast<const float4*>(dwe + brow[j] + k0);
      ushort4 w; w.x = f2bf(v.x); w.y = f2bf(v.y); w.z = f2bf(v.z); w.w = f2bf(v.w);
      *reinterpret_cast<ushort4*>(&Bs[bwr[j]]) = w;
    }
    __syncthreads();
#pragma unroll
    for (int kk = 0; kk < 64; kk += 32) {
      bf16x8 a[4], b[2];
#pragma unroll
      for (int m = 0; m < 4; ++m) {
        int ar = wm * 64 + m * 16 + fr;
        a[m] = *reinterpret_cast<const bf16x8*>(&As[lds_idx(ar, kk + fk)]);
      }
#pragma unroll
      for (int n = 0; n < 2; ++n) {
        int br = wn * 32 + n * 16 + fr;
        b[n] = *reinterpret_cast<const bf16x8*>(&Bs[lds_idx(br, kk + fk)]);
      }
#pragma unroll
      for (int m = 0; m < 4; ++m)
#pragma unroll
        for (int n = 0; n < 2; ++n)
          acc[m][n] = __builtin_amdgcn_mfma_f32_16x16x32_bf16(a[m], b[n], acc[m][n], 0, 0, 0);
    }
  }

  const int rb = mb * 128 + wm * 64 + (lane >> 4) * 4;
  const int cb = bn * 128 + wn * 32 + fr;
#pragma unroll
  for (int m = 0; m < 4; ++m) {
#pragma unroll
    for (int r = 0; r < 4; ++r) {
      int rl = rb + m * 16 + r;
      if (EXPERT && rl >= cnt_e) continue;
#pragma unroll
      for (int n = 0; n < 2; ++n)
        yout[(size_t)(rowoff + rl) * DIM_ + cb + n * 16] = acc[m][n][r];
    }
  }
}

// ---------------- finalize: out = y_shared + w0*y0 + w1*y1 ----------------
__global__ __launch_bounds__(256) void finalize_kernel(
    const float* __restrict__ ys, const float* __restrict__ yb,
    const int* __restrict__ slot, const float* __restrict__ tw,
    const int* __restrict__ off, float* __restrict__ out) {
  int i = blockIdx.x * 256 + threadIdx.x;
  int t = i >> 8, c4 = (i & 255) * 4;
  int s0 = slot[t * 2], s1 = slot[t * 2 + 1];
  float w0 = tw[t * 2], w1 = tw[t * 2 + 1];
  size_t r0 = (size_t)(off[s0 >> 16] + (s0 & 0xFFFF)) * DIM_ + c4;
  size_t r1 = (size_t)(off[s1 >> 16] + (s1 & 0xFFFF)) * DIM_ + c4;
  float4 a  = *reinterpret_cast<const float4*>(ys + (size_t)t * DIM_ + c4);
  float4 b0 = *reinterpret_cast<const float4*>(yb + r0);
  float4 b1 = *reinterpret_cast<const float4*>(yb + r1);
  float4 o;
  o.x = a.x + w0 * b0.x + w1 * b1.x;
  o.y = a.y + w0 * b0.y + w1 * b1.y;
  o.z = a.z + w0 * b0.z + w1 * b1.z;
  o.w = a.w + w0 * b0.w + w1 * b1.w;
  *reinterpret_cast<float4*>(out + (size_t)t * DIM_ + c4) = o;
}

extern "C" void kernel_launch(void* const* d_in, const int* in_sizes, int n_in,
                              void* d_out, int out_size, void* d_ws, size_t ws_size,
                              hipStream_t stream) {
  const float* x    = (const float*)d_in[0];
  const float* rw   = (const float*)d_in[1];
  const float* bias = (const float*)d_in[2];
  const float* gw   = (const float*)d_in[3];
  const float* uw   = (const float*)d_in[4];
  const float* dwn  = (const float*)d_in[5];
  const float* sgw  = (const float*)d_in[6];
  const float* suw  = (const float*)d_in[7];
  const float* sdw  = (const float*)d_in[8];
  float* out = (float*)d_out;

  char* ws = (char*)d_ws;
  size_t o = 0;
  auto alloc = [&](size_t b) { size_t r = o; o = (o + b + 255) & ~(size_t)255; return r; };
  unsigned short* xhi = (unsigned short*)(ws + alloc((size_t)T_TOK * DIM_ * 2));
  unsigned short* xlo = (unsigned short*)(ws + alloc((size_t)T_TOK * DIM_ * 2));
  unsigned short* h   = (unsigned short*)(ws + alloc(((size_t)2 * T_TOK + 128) * HID_ * 2));
  float* yshared = (float*)(ws + alloc((size_t)T_TOK * DIM_ * 4));
  float* ybuf    = (float*)(ws + alloc((size_t)2 * T_TOK * DIM_ * 4));
  int* cnt  = (int*)(ws + alloc(NEXP * 4));
  int* off  = (int*)(ws + alloc(NEXP * 4));
  int* list = (int*)(ws + alloc((size_t)NEXP * T_TOK * 4));
  int* slot = (int*)(ws + alloc((size_t)2 * T_TOK * 4));
  float* tw = (float*)(ws + alloc((size_t)2 * T_TOK * 4));
  size_t need_base = o;
  // bf16 weight pre-cast region (optional)
  const size_t WE = (size_t)HID_ * DIM_;      // elements per matrix
  unsigned short* gwb  = (unsigned short*)(ws + alloc(NEXP * WE * 2));
  unsigned short* uwb  = (unsigned short*)(ws + alloc(NEXP * WE * 2));
  unsigned short* dwb  = (unsigned short*)(ws + alloc(NEXP * WE * 2));
  unsigned short* sgwb = (unsigned short*)(ws + alloc(WE * 2));
  unsigned short* suwb = (unsigned short*)(ws + alloc(WE * 2));
  unsigned short* sdwb = (unsigned short*)(ws + alloc(WE * 2));
  const bool precast = (o <= ws_size);
  if (!precast && need_base > ws_size) {  // cannot run at all: fail visibly
    hipMemsetAsync(d_out, 0, (size_t)out_size * 4, stream);
    return;
  }

  hipMemsetAsync(cnt, 0, NEXP * 4, stream);
  cast_x_kernel<<<T_TOK * DIM_ / 8 / 256, 256, 0, stream>>>(x, xhi, xlo);
  router_kernel<<<T_TOK / 4, 256, 0, stream>>>(x, rw, bias, cnt, list, slot, tw);
  scan_kernel<<<1, 64, 0, stream>>>(cnt, off);

  if (precast) {
    const int WB = (int)(NEXP * WE / 2048);   // blocks for 8-expert matrix
    const int WS = (int)(WE / 2048);          // blocks for shared matrix
    cast_w_kernel<<<WB, 256, 0, stream>>>(gw,  gwb);
    cast_w_kernel<<<WB, 256, 0, stream>>>(uw,  uwb);
    cast_w_kernel<<<WB, 256, 0, stream>>>(dwn, dwb);
    cast_w_kernel<<<WS, 256, 0, stream>>>(sgw, sgwb);
    cast_w_kernel<<<WS, 256, 0, stream>>>(suw, suwb);
    cast_w_kernel<<<WS, 256, 0, stream>>>(sdw, sdwb);
    gateup_bf16<false><<<dim3(HID_ / 128, T_TOK / 128, 1), 512, 0, stream>>>(
        xhi, xlo, sgwb, suwb, cnt, off, list, h);
    down_bf16<false><<<dim3(DIM_ / 128, T_TOK / 128, 1), 512, 0, stream>>>(
        h, sdwb, cnt, off, yshared);
    gateup_bf16<true><<<dim3(HID_ / 128, T_TOK / 128, NEXP), 512, 0, stream>>>(
        xhi, xlo, gwb, uwb, cnt, off, list, h);
    down_bf16<true><<<dim3(DIM_ / 128, T_TOK / 128, NEXP), 512, 0, stream>>>(
        h, dwb, cnt, off, ybuf);
  } else {
    gateup_kernel<false><<<dim3(HID_ / 128, T_TOK / 128, 1), 512, 0, stream>>>(
        xhi, xlo, sgw, suw, cnt, off, list, h);
    down_kernel<false><<<dim3(DIM_ / 128, T_TOK / 128, 1), 512, 0, stream>>>(
        h, sdw, cnt, off, yshared);
    gateup_kernel<true><<<dim3(HID_ / 128, T_TOK / 128, NEXP), 512, 0, stream>>>(
        xhi, xlo, gw, uw, cnt, off, list, h);
    down_kernel<true><<<dim3(DIM_ / 128, T_TOK / 128, NEXP), 512, 0, stream>>>(
        h, dwn, cnt, off, ybuf);
  }
  finalize_kernel<<<T_TOK * (DIM_ / 4) / 256, 256, 0, stream>>>(
      yshared, ybuf, slot, tw, off, out);
}

// Round 7
// 1085.724 us; speedup vs baseline: 3.0749x; 1.9976x over previous
//
#include <hip/hip_runtime.h>
#include <hip/hip_bf16.h>
#include <stdint.h>

#define T_TOK  8192
#define DIM_   1024
#define HID_   2816
#define NEXP   8

typedef __bf16 bf16x8 __attribute__((ext_vector_type(8)));
typedef float  f32x4  __attribute__((ext_vector_type(4)));

__device__ __forceinline__ unsigned short f2bf(float f) {
  uint32_t u = __float_as_uint(f);
  u += 0x7FFFu + ((u >> 16) & 1u);
  return (unsigned short)(u >> 16);
}

__device__ __forceinline__ void gld_lds16(const void* g, void* l) {
  __builtin_amdgcn_global_load_lds(
      (const __attribute__((address_space(1))) uint32_t*)g,
      (__attribute__((address_space(3))) uint32_t*)l, 16, 0, 0);
}

// Swizzled LDS index for a [*][64]-ushort tile: 16B unit (col>>3) XOR (row&7).
__device__ __forceinline__ int lds_idx(int row, int col) {
  return row * 64 + ((((col >> 3) ^ (row & 7)) & 7) << 3);
}

// ---------------- cast x fp32 -> bf16 ----------------
__global__ __launch_bounds__(256) void cast_x_kernel(const float* __restrict__ in,
                                                     unsigned short* __restrict__ out) {
  int i = (blockIdx.x * 256 + threadIdx.x) * 8;
#pragma unroll
  for (int half = 0; half < 2; ++half) {
    float4 a = *reinterpret_cast<const float4*>(in + i + half * 4);
    ushort4 h4;
    h4.x = f2bf(a.x); h4.y = f2bf(a.y); h4.z = f2bf(a.z); h4.w = f2bf(a.w);
    *reinterpret_cast<ushort4*>(out + i + half * 4) = h4;
  }
}

// ---------------- cast weights fp32 -> bf16 ----------------
__global__ __launch_bounds__(256) void cast_w_kernel(const float* __restrict__ in,
                                                     unsigned short* __restrict__ out) {
  size_t i = ((size_t)blockIdx.x * 256 + threadIdx.x) * 8;
#pragma unroll
  for (int half = 0; half < 2; ++half) {
    float4 a = *reinterpret_cast<const float4*>(in + i + half * 4);
    ushort4 h4;
    h4.x = f2bf(a.x); h4.y = f2bf(a.y); h4.z = f2bf(a.z); h4.w = f2bf(a.w);
    *reinterpret_cast<ushort4*>(out + i + half * 4) = h4;
  }
}

// ---------------- router: sigmoid top-2 + token lists + weights ----------------
__global__ __launch_bounds__(256) void router_kernel(
    const float* __restrict__ x, const float* __restrict__ rw,
    const float* __restrict__ bias, int* __restrict__ cnt,
    int* __restrict__ list, float* __restrict__ wlist) {
  __shared__ float rws[NEXP * DIM_];
  for (int i = threadIdx.x; i < NEXP * DIM_ / 4; i += 256)
    reinterpret_cast<float4*>(rws)[i] = reinterpret_cast<const float4*>(rw)[i];
  __syncthreads();
  int wave = threadIdx.x >> 6, lane = threadIdx.x & 63;
  int t = blockIdx.x * 4 + wave;
  const float* xr = x + (size_t)t * DIM_;
  float p[NEXP];
#pragma unroll
  for (int e = 0; e < NEXP; ++e) p[e] = 0.f;
  for (int i = 0; i < DIM_ / 64; ++i) {
    float xv = xr[i * 64 + lane];
#pragma unroll
    for (int e = 0; e < NEXP; ++e) p[e] += xv * rws[e * DIM_ + i * 64 + lane];
  }
#pragma unroll
  for (int e = 0; e < NEXP; ++e) {
#pragma unroll
    for (int s = 32; s > 0; s >>= 1) p[e] += __shfl_xor(p[e], s);
  }
  if (lane == 0) {
    float sc[NEXP];
#pragma unroll
    for (int e = 0; e < NEXP; ++e) sc[e] = 1.f / (1.f + __expf(-(p[e] + bias[e])));
    int e0 = 0; float s0 = sc[0];
#pragma unroll
    for (int e = 1; e < NEXP; ++e) if (sc[e] > s0) { s0 = sc[e]; e0 = e; }
    int e1 = -1; float s1 = -1.f;
#pragma unroll
    for (int e = 0; e < NEXP; ++e) if (e != e0 && sc[e] > s1) { s1 = sc[e]; e1 = e; }
    float inv = 1.f / (s0 + s1 + 1e-6f);
    int p0 = atomicAdd(&cnt[e0], 1);
    list[e0 * T_TOK + p0] = t; wlist[e0 * T_TOK + p0] = s0 * inv;
    int p1 = atomicAdd(&cnt[e1], 1);
    list[e1 * T_TOK + p1] = t; wlist[e1 * T_TOK + p1] = s1 * inv;
  }
}

// ---------------- tiny exclusive scan over 8 counts ----------------
__global__ void scan_kernel(const int* __restrict__ cnt, int* __restrict__ off) {
  if (threadIdx.x == 0) {
    int a = 0;
#pragma unroll
    for (int e = 0; e < NEXP; ++e) { off[e] = a; a += cnt[e]; }
  }
}

// ==================================================================
// gate+up GEMM + silu -> h (bf16). A = gathered xbf rows.
// WBF16: B staged via global_load_lds (pre-swizzled src); else fp32 reg-convert.
// Grid: x = bn (fast), y = mb, z = expert.
// ==================================================================
template <bool EXPERT, bool WBF16>
__global__ __launch_bounds__(512) void gateup_k(
    const unsigned short* __restrict__ xbf,
    const void* __restrict__ gw_, const void* __restrict__ uw_,
    const int* __restrict__ cnt, const int* __restrict__ off,
    const int* __restrict__ list, unsigned short* __restrict__ hout) {
  const int e = EXPERT ? blockIdx.z : 0;
  const int cnt_e = EXPERT ? cnt[e] : T_TOK;
  const int bn = blockIdx.x, mb = blockIdx.y;
  if (mb * 128 >= cnt_e) return;
  const int rowoff = EXPERT ? off[e] : 0;

  __shared__ unsigned short As[128 * 64];
  __shared__ unsigned short Bg[128 * 64];
  __shared__ unsigned short Bu[128 * 64];

  const int tid = threadIdx.x;
  const size_t eoff = EXPERT ? (size_t)e * HID_ * DIM_ : 0;
  const unsigned short* gwb = WBF16 ? (const unsigned short*)gw_ + eoff : nullptr;
  const unsigned short* uwb = WBF16 ? (const unsigned short*)uw_ + eoff : nullptr;
  const float* gwf = WBF16 ? nullptr : (const float*)gw_ + eoff;
  const float* uwf = WBF16 ? nullptr : (const float*)uw_ + eoff;

  // chunk c -> LDS row r=c>>3, unit c&7; global k-unit u=(c&7)^(r&7) (pre-swizzled src)
  size_t arow[2], brow[2];
#pragma unroll
  for (int j = 0; j < 2; ++j) {
    int c = tid + j * 512;
    int r = c >> 3;
    int u = (c & 7) ^ (r & 7);
    int rl = mb * 128 + r;
    int gr;
    if (EXPERT) { int cl = rl < cnt_e ? rl : cnt_e - 1; gr = list[e * T_TOK + cl]; }
    else gr = rl;
    arow[j] = (size_t)gr * DIM_ + (size_t)(u * 8);
    brow[j] = (size_t)(bn * 128 + r) * DIM_ + (size_t)(u * 8);
  }
  // fp32-B path: float4 f -> row f>>4, 8B slot s=f&15; swizzled ds_write addr
  size_t brow4[4];
  int bwr4[4];
  if (!WBF16) {
#pragma unroll
    for (int j = 0; j < 4; ++j) {
      int f = tid + j * 512;
      int rb = f >> 4, s = f & 15;
      bwr4[j] = rb * 64 + (((s >> 1) ^ (rb & 7)) * 2 + (s & 1)) * 4;
      brow4[j] = (size_t)(bn * 128 + rb) * DIM_ + (size_t)(s * 4);
    }
  }

  const f32x4 vzero = {0.f, 0.f, 0.f, 0.f};
  f32x4 accg[4][2], accu[4][2];
#pragma unroll
  for (int m = 0; m < 4; ++m)
#pragma unroll
    for (int n = 0; n < 2; ++n) { accg[m][n] = vzero; accu[m][n] = vzero; }

  const int wid = tid >> 6, lane = tid & 63;
  const int wm = wid >> 2, wn = wid & 3;
  const int fr = lane & 15, fk = (lane >> 4) * 8;

  for (int k0 = 0; k0 < DIM_; k0 += 64) {
    __syncthreads();
#pragma unroll
    for (int j = 0; j < 2; ++j) {
      int c = tid + j * 512;
      gld_lds16(xbf + arow[j] + k0, &As[c * 8]);
      if (WBF16) {
        gld_lds16(gwb + brow[j] + k0, &Bg[c * 8]);
        gld_lds16(uwb + brow[j] + k0, &Bu[c * 8]);
      }
    }
    if (!WBF16) {
#pragma unroll
      for (int j = 0; j < 4; ++j) {
        float4 vg = *reinterpret_cast<const float4*>(gwf + brow4[j] + k0);
        float4 vu = *reinterpret_cast<const float4*>(uwf + brow4[j] + k0);
        ushort4 wg; wg.x = f2bf(vg.x); wg.y = f2bf(vg.y); wg.z = f2bf(vg.z); wg.w = f2bf(vg.w);
        ushort4 wu; wu.x = f2bf(vu.x); wu.y = f2bf(vu.y); wu.z = f2bf(vu.z); wu.w = f2bf(vu.w);
        *reinterpret_cast<ushort4*>(&Bg[bwr4[j]]) = wg;
        *reinterpret_cast<ushort4*>(&Bu[bwr4[j]]) = wu;
      }
    }
    __syncthreads();
#pragma unroll
    for (int kk = 0; kk < 64; kk += 32) {
      bf16x8 a[4], bg[2], bu[2];
#pragma unroll
      for (int m = 0; m < 4; ++m) {
        int ar = wm * 64 + m * 16 + fr;
        a[m] = *reinterpret_cast<const bf16x8*>(&As[lds_idx(ar, kk + fk)]);
      }
#pragma unroll
      for (int n = 0; n < 2; ++n) {
        int br = wn * 32 + n * 16 + fr;
        bg[n] = *reinterpret_cast<const bf16x8*>(&Bg[lds_idx(br, kk + fk)]);
        bu[n] = *reinterpret_cast<const bf16x8*>(&Bu[lds_idx(br, kk + fk)]);
      }
#pragma unroll
      for (int m = 0; m < 4; ++m)
#pragma unroll
        for (int n = 0; n < 2; ++n) {
          accg[m][n] = __builtin_amdgcn_mfma_f32_16x16x32_bf16(a[m], bg[n], accg[m][n], 0, 0, 0);
          accu[m][n] = __builtin_amdgcn_mfma_f32_16x16x32_bf16(a[m], bu[n], accu[m][n], 0, 0, 0);
        }
    }
  }

  const int rb = mb * 128 + wm * 64 + (lane >> 4) * 4;
  const int cb = bn * 128 + wn * 32 + fr;
#pragma unroll
  for (int m = 0; m < 4; ++m) {
#pragma unroll
    for (int r = 0; r < 4; ++r) {
      int rl = rb + m * 16 + r;
      if (EXPERT && rl >= cnt_e) continue;
      size_t rowbase = (size_t)(rowoff + rl) * HID_ + cb;
#pragma unroll
      for (int n = 0; n < 2; ++n) {
        float g = accg[m][n][r], u = accu[m][n][r];
        float hv = (g / (1.f + __expf(-g))) * u;
        hout[rowbase + n * 16] = f2bf(hv);
      }
    }
  }
}

// ==================================================================
// down GEMM fused epilogue: out[token] += w_e * (h . dw^T)
// ==================================================================
template <bool EXPERT, bool WBF16>
__global__ __launch_bounds__(512) void down_k(
    const unsigned short* __restrict__ h, const void* __restrict__ dw_,
    const int* __restrict__ cnt, const int* __restrict__ off,
    const int* __restrict__ list, const float* __restrict__ wlist,
    float* __restrict__ out) {
  const int e = EXPERT ? blockIdx.z : 0;
  const int cnt_e = EXPERT ? cnt[e] : T_TOK;
  const int bn = blockIdx.x, mb = blockIdx.y;
  if (mb * 128 >= cnt_e) return;
  const int rowoff = EXPERT ? off[e] : 0;

  __shared__ unsigned short As[128 * 64];
  __shared__ unsigned short Bs[128 * 64];

  const int tid = threadIdx.x;
  const size_t eoff = EXPERT ? (size_t)e * DIM_ * HID_ : 0;
  const unsigned short* dwb = WBF16 ? (const unsigned short*)dw_ + eoff : nullptr;
  const float* dwf = WBF16 ? nullptr : (const float*)dw_ + eoff;

  size_t arow[2], brow[2];
#pragma unroll
  for (int j = 0; j < 2; ++j) {
    int c = tid + j * 512;
    int r = c >> 3;
    int u = (c & 7) ^ (r & 7);
    int rl = mb * 128 + r;
    int cl = (EXPERT && rl >= cnt_e) ? cnt_e - 1 : rl;
    arow[j] = (size_t)(rowoff + cl) * HID_ + (size_t)(u * 8);
    brow[j] = (size_t)(bn * 128 + r) * HID_ + (size_t)(u * 8);
  }
  size_t brow4[4];
  int bwr4[4];
  if (!WBF16) {
#pragma unroll
    for (int j = 0; j < 4; ++j) {
      int f = tid + j * 512;
      int rb = f >> 4, s = f & 15;
      bwr4[j] = rb * 64 + (((s >> 1) ^ (rb & 7)) * 2 + (s & 1)) * 4;
      brow4[j] = (size_t)(bn * 128 + rb) * HID_ + (size_t)(s * 4);
    }
  }

  const f32x4 vzero = {0.f, 0.f, 0.f, 0.f};
  f32x4 acc[4][2];
#pragma unroll
  for (int m = 0; m < 4; ++m)
#pragma unroll
    for (int n = 0; n < 2; ++n) acc[m][n] = vzero;

  const int wid = tid >> 6, lane = tid & 63;
  const int wm = wid >> 2, wn = wid & 3;
  const int fr = lane & 15, fk = (lane >> 4) * 8;

  for (int k0 = 0; k0 < HID_; k0 += 64) {
    __syncthreads();
#pragma unroll
    for (int j = 0; j < 2; ++j) {
      int c = tid + j * 512;
      gld_lds16(h + arow[j] + k0, &As[c * 8]);
      if (WBF16) gld_lds16(dwb + brow[j] + k0, &Bs[c * 8]);
    }
    if (!WBF16) {
#pragma unroll
      for (int j = 0; j < 4; ++j) {
        float4 v = *reinterpret_cast<const float4*>(dwf + brow4[j] + k0);
        ushort4 w; w.x = f2bf(v.x); w.y = f2bf(v.y); w.z = f2bf(v.z); w.w = f2bf(v.w);
        *reinterpret_cast<ushort4*>(&Bs[bwr4[j]]) = w;
      }
    }
    __syncthreads();
#pragma unroll
    for (int kk = 0; kk < 64; kk += 32) {
      bf16x8 a[4], b[2];
#pragma unroll
      for (int m = 0; m < 4; ++m) {
        int ar = wm * 64 + m * 16 + fr;
        a[m] = *reinterpret_cast<const bf16x8*>(&As[lds_idx(ar, kk + fk)]);
      }
#pragma unroll
      for (int n = 0; n < 2; ++n) {
        int br = wn * 32 + n * 16 + fr;
        b[n] = *reinterpret_cast<const bf16x8*>(&Bs[lds_idx(br, kk + fk)]);
      }
#pragma unroll
      for (int m = 0; m < 4; ++m)
#pragma unroll
        for (int n = 0; n < 2; ++n)
          acc[m][n] = __builtin_amdgcn_mfma_f32_16x16x32_bf16(a[m], b[n], acc[m][n], 0, 0, 0);
    }
  }

  const int rb = mb * 128 + wm * 64 + (lane >> 4) * 4;
  const int cb = bn * 128 + wn * 32 + fr;
#pragma unroll
  for (int m = 0; m < 4; ++m) {
#pragma unroll
    for (int r = 0; r < 4; ++r) {
      int rl = rb + m * 16 + r;
      if (EXPERT && rl >= cnt_e) continue;
      int tok; float w;
      if (EXPERT) { tok = list[e * T_TOK + rl]; w = wlist[e * T_TOK + rl]; }
      else { tok = rl; w = 1.f; }
      float* orow = out + (size_t)tok * DIM_ + cb;
#pragma unroll
      for (int n = 0; n < 2; ++n)
        atomicAdd(orow + n * 16, w * acc[m][n][r]);
    }
  }
}

extern "C" void kernel_launch(void* const* d_in, const int* in_sizes, int n_in,
                              void* d_out, int out_size, void* d_ws, size_t ws_size,
                              hipStream_t stream) {
  const float* x    = (const float*)d_in[0];
  const float* rw   = (const float*)d_in[1];
  const float* bias = (const float*)d_in[2];
  const float* gw   = (const float*)d_in[3];
  const float* uw   = (const float*)d_in[4];
  const float* dwn  = (const float*)d_in[5];
  const float* sgw  = (const float*)d_in[6];
  const float* suw  = (const float*)d_in[7];
  const float* sdw  = (const float*)d_in[8];
  float* out = (float*)d_out;

  char* ws = (char*)d_ws;
  size_t o = 0;
  auto alloc = [&](size_t b) { size_t r = o; o = (o + b + 255) & ~(size_t)255; return r; };
  unsigned short* xbf = (unsigned short*)(ws + alloc((size_t)T_TOK * DIM_ * 2));
  unsigned short* h   = (unsigned short*)(ws + alloc(((size_t)2 * T_TOK + 128) * HID_ * 2));
  int*   cnt   = (int*)(ws + alloc(NEXP * 4));
  int*   off   = (int*)(ws + alloc(NEXP * 4));
  int*   list  = (int*)(ws + alloc((size_t)NEXP * T_TOK * 4));
  float* wlist = (float*)(ws + alloc((size_t)NEXP * T_TOK * 4));
  const size_t need_base = o;
  // tiered bf16 weight pre-cast region
  const size_t WE = (size_t)HID_ * DIM_;
  unsigned short* gwb  = (unsigned short*)(ws + alloc(NEXP * WE * 2));
  unsigned short* uwb  = (unsigned short*)(ws + alloc(NEXP * WE * 2));
  const bool pcGU = (o <= ws_size);
  unsigned short* dwb  = (unsigned short*)(ws + alloc(NEXP * WE * 2));
  const bool pcDN = (o <= ws_size);
  unsigned short* sgwb = (unsigned short*)(ws + alloc(WE * 2));
  unsigned short* suwb = (unsigned short*)(ws + alloc(WE * 2));
  unsigned short* sdwb = (unsigned short*)(ws + alloc(WE * 2));
  const bool pcSH = (o <= ws_size);
  if (need_base > ws_size) {  // cannot run at all: fail visibly
    hipMemsetAsync(d_out, 0, (size_t)out_size * 4, stream);
    return;
  }

  hipMemsetAsync(out, 0, (size_t)out_size * 4, stream);
  hipMemsetAsync(cnt, 0, NEXP * 4, stream);
  cast_x_kernel<<<T_TOK * DIM_ / 8 / 256, 256, 0, stream>>>(x, xbf);
  router_kernel<<<T_TOK / 4, 256, 0, stream>>>(x, rw, bias, cnt, list, wlist);
  scan_kernel<<<1, 64, 0, stream>>>(cnt, off);

  const int WB = (int)(NEXP * WE / 2048);
  const int WS = (int)(WE / 2048);
  if (pcGU) {
    cast_w_kernel<<<WB, 256, 0, stream>>>(gw, gwb);
    cast_w_kernel<<<WB, 256, 0, stream>>>(uw, uwb);
  }
  if (pcDN) cast_w_kernel<<<WB, 256, 0, stream>>>(dwn, dwb);
  if (pcSH) {
    cast_w_kernel<<<WS, 256, 0, stream>>>(sgw, sgwb);
    cast_w_kernel<<<WS, 256, 0, stream>>>(suw, suwb);
    cast_w_kernel<<<WS, 256, 0, stream>>>(sdw, sdwb);
  }

  // shared expert (h rows 0..T-1, then reused by routed pass)
  if (pcSH) {
    gateup_k<false, true><<<dim3(HID_ / 128, T_TOK / 128, 1), 512, 0, stream>>>(
        xbf, sgwb, suwb, cnt, off, list, h);
    down_k<false, true><<<dim3(DIM_ / 128, T_TOK / 128, 1), 512, 0, stream>>>(
        h, sdwb, cnt, off, list, wlist, out);
  } else {
    gateup_k<false, false><<<dim3(HID_ / 128, T_TOK / 128, 1), 512, 0, stream>>>(
        xbf, sgw, suw, cnt, off, list, h);
    down_k<false, false><<<dim3(DIM_ / 128, T_TOK / 128, 1), 512, 0, stream>>>(
        h, sdw, cnt, off, list, wlist, out);
  }
  // routed experts (worst-case grid, early-exit on cnt)
  if (pcGU)
    gateup_k<true, true><<<dim3(HID_ / 128, T_TOK / 128, NEXP), 512, 0, stream>>>(
        xbf, gwb, uwb, cnt, off, list, h);
  else
    gateup_k<true, false><<<dim3(HID_ / 128, T_TOK / 128, NEXP), 512, 0, stream>>>(
        xbf, gw, uw, cnt, off, list, h);
  if (pcDN)
    down_k<true, true><<<dim3(DIM_ / 128, T_TOK / 128, NEXP), 512, 0, stream>>>(
        h, dwb, cnt, off, list, wlist, out);
  else
    down_k<true, false><<<dim3(DIM_ / 128, T_TOK / 128, NEXP), 512, 0, stream>>>(
        h, dwn, cnt, off, list, wlist, out);
}